// Round 8
// baseline (90.329 us; speedup 1.0000x reference)
//
#include <hip/hip_runtime.h>
#include <math.h>

#define NROWS 8192
#define DDIM  128
#define K20   28.853900817779268f        // 20 * log2(e)
#define K2    (K20 * K20)                // 832.5476
#define DTHR  8.3255f                    // 0.01 * K2 (finalize subtraction mimic only)

typedef _Float16 f16x8 __attribute__((ext_vector_type(8)));
typedef _Float16 f16x4 __attribute__((ext_vector_type(4)));
typedef _Float16 f16x2 __attribute__((ext_vector_type(2)));
typedef float    f32x4 __attribute__((ext_vector_type(4)));

#ifndef __has_builtin
#define __has_builtin(x) 0
#endif
#if __has_builtin(__builtin_amdgcn_fdot2)
#define HAVE_FDOT2 1
#else
#define HAVE_FDOT2 0
#endif

// Fragment-major layout for mfma_f32_16x16x32_f16 (16-row groups):
//   xf[g*2048 + kk*512 + l*8 + j] = x[i = g*16 + (l&15)][k = kk*32 + (l>>4)*8 + j]
// ws layout (floats after xf): sums[0..N) = nL (sum exp(-40d)), [N..2N) = nS (sum exp(-20d))
//
// Triangle, balanced to ONE residency generation (the R7 straggler fix):
//   row strip s (128 rows) keeps 16-col tiles t in [8s, 512)  (count 512-8s);
//   strips s and 63-s pair into a 520-tile ribbon (constant!).
//   Grid = 32 ribbons x 32 blocks = 1024 blocks, each u in [65q>>2, 65(q+1)>>2)
//   = 16 or 17 tiles, split into <=2 phases (one per strip side).
//   Each strictly-upper element (j>i) is accumulated once: direct into row i
//   (row-sum reduce + atomic) and mirrored into row j (col sums staged in LDS,
//   one atomic per column per phase).

// ---- fp32 -> f16 frag-major transform + zero sums/out ----
__global__ void convert_kernel(const float* __restrict__ x,
                               _Float16* __restrict__ xf,
                               float* __restrict__ sums,
                               float* __restrict__ out) {
    int idx = (blockIdx.x * 256 + threadIdx.x) * 4;    // flat (i,k) element index
    float4 v = *(const float4*)(x + idx);
    f16x4 h = { (_Float16)v.x, (_Float16)v.y, (_Float16)v.z, (_Float16)v.w };
    const int i = idx >> 7, k = idx & 127;             // k multiple of 4
    const int lane = (((k >> 3) & 3) << 4) | (i & 15);
    const int dst = (i >> 4) * 2048 + (k >> 5) * 512 + lane * 8 + (k & 7);
    *(f16x4*)(xf + dst) = h;
    if (threadIdx.x < 16) sums[blockIdx.x * 16 + threadIdx.x] = 0.0f;  // 1024*16 = 2*NROWS
    if (blockIdx.x == 0 && threadIdx.x == 0) out[0] = 0.0f;
}

// ---- balanced symmetric pair kernel: 1024 blocks, 16-17 tiles each ----
__global__ __launch_bounds__(256, 4) void pair_kernel(
        const _Float16* __restrict__ xf,
        float* __restrict__ sums) {
    __shared__ float shcL[4][272], shcS[4][272];   // 8.7 KB: per-wave col sums

    const int bq = blockIdx.x;
    const int p  = bq >> 5;                        // ribbon (strip-pair) 0..31
    const int q  = bq & 31;                        // chunk within ribbon
    const int u0 = (65 * q) >> 2;                  // ribbon tile range [u0, u1)
    const int u1 = (65 * (q + 1)) >> 2;
    const int C1 = 512 - 8 * p;                    // ribbon tiles from strip p

    const int w = threadIdx.x >> 6;
    const int lane = threadIdx.x & 63;

    #pragma unroll 1
    for (int ph = 0; ph < 2; ++ph) {
        // phase A: strip p, tiles 8p+u for u in [u0, min(u1,C1))
        // phase B: strip 63-p, tiles (504-8p)+(u-C1) for u in [max(u0,C1), u1)
        int s, ta, tb;
        if (ph == 0) {
            const int ua = u0, ub = (u1 < C1) ? u1 : C1;
            if (ua >= ub) continue;                // block-uniform
            s = p; ta = 8 * p + ua; tb = 8 * p + ub;
        } else {
            const int ua = (u0 > C1) ? u0 : C1, ub = u1;
            if (ua >= ub) continue;                // block-uniform
            s = 63 - p; ta = 504 - 8 * p + (ua - C1); tb = 504 - 8 * p + (ub - C1);
        }
        const int rowb = s * 128 + w * 32;         // wave's first row

        // A fragments for this strip: 2x4 coalesced 1 KB loads
        const _Float16* ab = xf + (size_t)(s * 8 + w * 2) * 2048 + lane * 8;
        f16x8 a0[4], a1[4];
        #pragma unroll
        for (int kk = 0; kk < 4; ++kk) {
            a0[kk] = *(const f16x8*)(ab + kk * 512);
            a1[kk] = *(const f16x8*)(ab + 2048 + kk * 512);
        }

        float nL[8], nS[8];
        #pragma unroll
        for (int r = 0; r < 8; ++r) { nL[r] = 0.f; nS[r] = 0.f; }

        auto loadB = [&](f16x8 (&b)[4], int t) {
            const _Float16* bp = xf + (size_t)t * 2048 + lane * 8;
            #pragma unroll
            for (int kk = 0; kk < 4; ++kk) b[kk] = *(const f16x8*)(bp + kk * 512);
        };
        auto compute = [&](f16x8 (&b)[4], int t) {
            f32x4 acc0 = {0.f,0.f,0.f,0.f}, acc1 = {0.f,0.f,0.f,0.f};
            #pragma unroll
            for (int kk = 0; kk < 4; ++kk) {
                acc0 = __builtin_amdgcn_mfma_f32_16x16x32_f16(a0[kk], b[kk], acc0, 0, 0, 0);
                acc1 = __builtin_amdgcn_mfma_f32_16x16x32_f16(a1[kk], b[kk], acc1, 0, 0, 0);
            }
            const int jcol = t * 16 + (lane & 15);
            float cs = 0.f, cl = 0.f;
            #pragma unroll
            for (int s2 = 0; s2 < 2; ++s2) {
                const int ib = rowb + s2 * 16 + ((lane >> 4) << 2);  // C/D row base
                #pragma unroll
                for (int r = 0; r < 4; ++r) {
                    float acc = s2 ? acc1[r] : acc0[r];
                    float d2s = fmaf(-2.0f * K2, acc, 2.0f * K2);    // (20*log2e)^2 d^2
                    float ds  = __builtin_amdgcn_sqrtf(d2s);         // NaN on self, masked
                    float tt  = __builtin_amdgcn_exp2f(-ds);         // exp(-20 d)
                    tt = (jcol > ib + r) ? tt : 0.0f;                // strictly-upper only
                    nS[s2 * 4 + r] += tt;
                    nL[s2 * 4 + r] = fmaf(tt, tt, nL[s2 * 4 + r]);   // exp(-40 d)
                    cs += tt;
                    cl = fmaf(tt, tt, cl);
                }
            }
            // mirror: reduce over this wave's 32 rows (row groups at lane bits 4,5)
            cs += __shfl_xor(cs, 16, 64);  cl += __shfl_xor(cl, 16, 64);
            cs += __shfl_xor(cs, 32, 64);  cl += __shfl_xor(cl, 32, 64);
            if (lane < 16) {
                shcS[w][(t - ta) * 16 + lane] = cs;
                shcL[w][(t - ta) * 16 + lane] = cl;
            }
        };

        // tile loop, 1-ahead register double buffer
        f16x8 b0[4], b1[4];
        loadB(b0, ta);
        int t = ta;
        for (; t + 2 <= tb; t += 2) {
            loadB(b1, t + 1);
            compute(b0, t);
            loadB(b0, (t + 2 < tb) ? t + 2 : ta);   // wrap prefetch: harmless
            compute(b1, t + 1);
        }
        if (t < tb) compute(b0, t);                 // odd-count tail

        // direct row sums: reduce across 16 column-lanes, atomic into sums[row]
        #pragma unroll
        for (int s2 = 0; s2 < 2; ++s2) {
            #pragma unroll
            for (int r = 0; r < 4; ++r) {
                float aa = nL[s2 * 4 + r], ss = nS[s2 * 4 + r];
                #pragma unroll
                for (int m = 1; m < 16; m <<= 1) {
                    aa += __shfl_xor(aa, m, 64);
                    ss += __shfl_xor(ss, m, 64);
                }
                if ((lane & 15) == 0) {
                    const int row = rowb + s2 * 16 + (lane >> 4) * 4 + r;
                    atomicAdd(&sums[row], aa);
                    atomicAdd(&sums[NROWS + row], ss);
                }
            }
        }

        // mirrored col sums: combine 4 waves, one atomic per column
        __syncthreads();
        const int nc = (tb - ta) * 16;
        for (int c = threadIdx.x; c < nc; c += 256) {
            const int col = ta * 16 + c;
            float mL = shcL[0][c] + shcL[1][c] + shcL[2][c] + shcL[3][c];
            float mS = shcS[0][c] + shcS[1][c] + shcS[2][c] + shcS[3][c];
            atomicAdd(&sums[col], mL);
            atomicAdd(&sums[NROWS + col], mS);
        }
        __syncthreads();                            // LDS reuse fence for phase B
    }
}

// ---- finalize + positive-pair correction, 8 threads per row (1024 waves).
//      (byte-identical to the round-7 verified kernel) ----
__global__ void finalize_kernel(const _Float16* __restrict__ xf,
                                const float* __restrict__ sums,
                                float* __restrict__ out) {
    const int tid = threadIdx.x;
    const int i = blockIdx.x * 32 + (tid >> 3);   // row
    const int j = tid & 7;                        // partner slot
    const int g = i >> 4, ri = i & 15, ii = i & 7;
    const _Float16* base = xf + (size_t)g * 2048;

    float pL = 0.f, pS = 0.f, subL = 0.f, subS = 0.f;
    if (j != ii) {
        const int rj = ri - ii + j;               // same 16-row group (classes 8-aligned)
        float dot = 0.f;
        #pragma unroll
        for (int kk = 0; kk < 4; ++kk) {
            #pragma unroll
            for (int h = 0; h < 4; ++h) {
                f16x8 av = *(const f16x8*)(base + kk * 512 + ((h << 4) | ri) * 8);
                f16x8 bv = *(const f16x8*)(base + kk * 512 + ((h << 4) | rj) * 8);
#if HAVE_FDOT2
                #pragma unroll
                for (int u = 0; u < 4; ++u) {
                    f16x2 pa = { av[2 * u], av[2 * u + 1] };
                    f16x2 pb = { bv[2 * u], bv[2 * u + 1] };
                    dot = __builtin_amdgcn_fdot2(pa, pb, dot, false);
                }
#else
                #pragma unroll
                for (int u = 0; u < 8; ++u)
                    dot = fmaf((float)av[u], (float)bv[u], dot);
#endif
            }
        }
        float d2 = fmaf(-2.f, dot, 2.f);
        float d  = sqrtf(fmaxf(d2, 1e-12f));           // reference clamp
        float tt = __builtin_amdgcn_exp2f(-d * K20);   // exp(-20 d)
        pS = __builtin_amdgcn_exp2f(d * K20);          // exp(+20 d)
        pL = tt * tt;
        float tp = (d2 * K2 < DTHR) ? 0.f : tt;        // what pair_kernel added
        subS = tp;
        subL = tp * tp;
    }

    // combine the 8 partner slots of this row
    #pragma unroll
    for (int m = 1; m < 8; m <<= 1) {
        pL   += __shfl_xor(pL, m, 64);
        pS   += __shfl_xor(pS, m, 64);
        subL += __shfl_xor(subL, m, 64);
        subS += __shfl_xor(subS, m, 64);
    }

    float v = 0.f;
    if (j == 0) {
        float nLv = sums[i] - subL;
        float nSv = sums[NROWS + i] - subS;
        float aLr  = 1.0f - pL / (pL + nLv);
        float posL = logf(pS) - 16.0f;    // log(sum exp(20(d-0.8)))
        float negL = logf(nSv) + 22.0f;   // log(sum exp(20(1.1-d)))
        v = aLr * (posL + negL);
    }
    #pragma unroll
    for (int m = 8; m < 64; m <<= 1) v += __shfl_xor(v, m, 64);

    __shared__ float partial[4];
    int wv = tid >> 6, lane = tid & 63;
    if (lane == 0) partial[wv] = v;
    __syncthreads();
    if (tid == 0) {
        float s = partial[0] + partial[1] + partial[2] + partial[3];
        atomicAdd(out, s * (1.0f / NROWS));
    }
}

extern "C" void kernel_launch(void* const* d_in, const int* in_sizes, int n_in,
                              void* d_out, int out_size, void* d_ws, size_t ws_size,
                              hipStream_t stream) {
    const float* x = (const float*)d_in[0];
    float* out = (float*)d_out;

    _Float16* xf = (_Float16*)d_ws;              // 2 MB, fragment-major
    float* sums  = (float*)(xf + NROWS * DDIM);  // 2*NROWS floats

    convert_kernel<<<NROWS * DDIM / (256 * 4), 256, 0, stream>>>(x, xf, sums, out);
    pair_kernel<<<1024, 256, 0, stream>>>(xf, sums);
    finalize_kernel<<<NROWS / 32, 256, 0, stream>>>(xf, sums, out);
}